// Round 11
// baseline (149.686 us; speedup 1.0000x reference)
//
#include <hip/hip_runtime.h>
#include <math.h>

// DirPNAConv: N=50000, E=800000, D=64, T=4, FI=FO=16.
// m[e] = Q[recv] + P[send] -> gather-stats of P + per-node Q shift (Q precomputed f16).
// Tower block-diagonality: post layer = per-tower K=64 GEMMs; x@Wx and postb folded
// through lin into Wfin/bfin. k_c: batched-prefetch tile loads, oT = W@aggT per tower
// (swapped operands), per-direction double-buffered wave-private LDS bounce,
// y^T = WfinT@[o1,o2,x]^T. Graph build: atomic-free counting sort.
// Gather: 16-lane-group-per-node, packed f16 accumulation.

typedef _Float16 half_t;
typedef __attribute__((ext_vector_type(8))) _Float16 half8;
typedef __attribute__((ext_vector_type(2))) _Float16 half2v;
typedef __attribute__((ext_vector_type(4))) float f32x4;

#define FCAP 12288

static __device__ __forceinline__ unsigned pkmin(unsigned a, unsigned b) {
    unsigned r;
    asm("v_pk_min_f16 %0, %1, %2" : "=v"(r) : "v"(a), "v"(b));
    return r;
}
static __device__ __forceinline__ unsigned pkmax(unsigned a, unsigned b) {
    unsigned r;
    asm("v_pk_max_f16 %0, %1, %2" : "=v"(r) : "v"(a), "v"(b));
    return r;
}
static __device__ __forceinline__ int h2i(half2v h) { return __builtin_bit_cast(int, h); }
static __device__ __forceinline__ half2v u2h(unsigned i) { return __builtin_bit_cast(half2v, i); }
static __device__ __forceinline__ half2v pkrtz(float a, float b) {
    return __builtin_bit_cast(half2v, __builtin_amdgcn_cvt_pkrtz(a, b));
}

// ---- fused: LDS edge histogram | weight prep | P,Q,xh projection ----
__global__ __launch_bounds__(256) void k_pre(
    const int* __restrict__ ei, int nE, int nN,
    int* __restrict__ histD, int* __restrict__ histS,
    const float* __restrict__ postW1, const float* __restrict__ postW2,
    const float* __restrict__ linW1, const float* __restrict__ linW2,
    const float* __restrict__ Wself, const float* __restrict__ bself,
    const float* __restrict__ linb1, const float* __restrict__ linb2,
    const float* __restrict__ postb1, const float* __restrict__ postb2,
    const float* __restrict__ alpha,
    half_t* __restrict__ WLg, half_t* __restrict__ WfinTg, float* __restrict__ bfin,
    const float* __restrict__ x,
    const float* __restrict__ preW1, const float* __restrict__ preW2,
    const float* __restrict__ preb1, const float* __restrict__ preb2,
    half_t* __restrict__ P1, half_t* __restrict__ P2,
    half_t* __restrict__ Q1, half_t* __restrict__ Q2, half_t* __restrict__ xh) {
    int tid = threadIdx.x;
    int b = blockIdx.x;
    if (b < 256) {
        __shared__ int hD[256], hS[256];
        hD[tid] = 0; hS[tid] = 0;
        __syncthreads();
        int chunk = (nE + 255) >> 8;
        int lo = b * chunk;
        int hi = lo + chunk; if (hi > nE) hi = nE;
        for (int e = lo + tid; e < hi; e += 256) {
            int s = ei[e], d = ei[nE + e];
            atomicAdd(&hD[d >> 8], 1);
            atomicAdd(&hS[s >> 8], 1);
        }
        __syncthreads();
        histD[tid * 256 + b] = hD[tid];
        histS[tid * 256 + b] = hS[tid];
    } else if (b < 320) {
        const float a = alpha[0];
        int id = (b - 256) * 256 + tid;
        const int stride = 64 * 256;
        for (int i = id; i < 24 * 16 * 72; i += stride) {
            int m = i / (16 * 72);
            int r = i % (16 * 72);
            int go = r / 72, k = r % 72;
            int d = m / 12, t = (m / 3) % 4, mat = m % 3;
            float v = 0.f;
            if (k < 64) {
                int stat = k >> 4, g = k & 15;
                int basep = (mat == 0) ? 1 : (mat == 1 ? 5 : 9);
                const float* pw = d ? postW2 : postW1;
                v = pw[t * 3328 + ((basep + stat) * 16 + g) * 16 + go];
            }
            WLg[i] = (half_t)v;
        }
        for (int i = id; i < 64 * 192; i += stride) {
            int o = i / 192, k = i % 192;
            float v;
            if (k < 64)       v = (1.f - a) * linW1[k * 64 + o];
            else if (k < 128) v = a * linW2[(k - 64) * 64 + o];
            else {
                int kx = k - 128, t = kx >> 4, f = kx & 15;
                v = Wself[kx * 64 + o];
                float s1 = 0.f, s2 = 0.f;
                for (int go = 0; go < 16; ++go) {
                    s1 += postW1[t * 3328 + f * 16 + go] * linW1[(t * 16 + go) * 64 + o];
                    s2 += postW2[t * 3328 + f * 16 + go] * linW2[(t * 16 + go) * 64 + o];
                }
                v += (1.f - a) * s1 + a * s2;
            }
            WfinTg[i] = (half_t)v;
        }
        for (int i = id; i < 64; i += stride) {
            float v = bself[i] + (1.f - a) * linb1[i] + a * linb2[i];
            for (int j = 0; j < 64; ++j)
                v += (1.f - a) * postb1[j] * linW1[j * 64 + i]
                   + a * postb2[j] * linW2[j * 64 + i];
            bfin[i] = v;
        }
    } else {
        int vb = b - 320;
        const int lane = tid & 63;
        const int t = lane >> 4, g = lane & 15;
        const int base = t << 4;
        float wsP1[16], wsP2[16], wsQ1[16], wsQ2[16];
#pragma unroll
        for (int f = 0; f < 16; ++f) {
            wsP1[f] = preW1[t * 512 + (16 + f) * 16 + g];
            wsP2[f] = preW2[t * 512 + (16 + f) * 16 + g];
            wsQ1[f] = preW1[t * 512 + f * 16 + g];
            wsQ2[f] = preW2[t * 512 + f * 16 + g];
        }
        const float pb1 = preb1[lane], pb2 = preb2[lane];
        int node = (vb * 256 + tid) >> 6;
        const int stride = (768 * 256) >> 6;
        for (; node < nN; node += stride) {
            float xv = x[(size_t)node * 64 + lane];
            float p1 = 0.f, p2 = 0.f, q1 = pb1, q2 = pb2;
#pragma unroll
            for (int f = 0; f < 16; ++f) {
                float v = __shfl(xv, base + f, 64);
                p1 = fmaf(v, wsP1[f], p1);
                p2 = fmaf(v, wsP2[f], p2);
                q1 = fmaf(v, wsQ1[f], q1);
                q2 = fmaf(v, wsQ2[f], q2);
            }
            size_t o = (size_t)node * 64 + lane;
            P1[o] = (half_t)p1;
            P2[o] = (half_t)p2;
            Q1[o] = (half_t)q1;
            Q2[o] = (half_t)q2;
            xh[o] = (half_t)xv;
        }
    }
}

// Two-level scan. scanA: per-1024 chunk local exclusive scan + chunk sums.
__global__ __launch_bounds__(256) void k_scanA(
    const int* __restrict__ cnt0, const int* __restrict__ cnt1,
    int* __restrict__ off0, int* __restrict__ off1,
    int* __restrict__ bsum, int n, int nchunk) {
    int arr = blockIdx.x >= nchunk;
    int c = blockIdx.x - (arr ? nchunk : 0);
    const int* cnt = arr ? cnt1 : cnt0;
    int* off = arr ? off1 : off0;
    int tid = threadIdx.x;
    int base = c * 1024 + tid * 4;
    int v[4];
#pragma unroll
    for (int k = 0; k < 4; ++k) { int i = base + k; v[k] = (i < n) ? cnt[i] : 0; }
    int tsum = v[0] + v[1] + v[2] + v[3];
    int lane = tid & 63, wid = tid >> 6;
    int incl = tsum;
#pragma unroll
    for (int d = 1; d < 64; d <<= 1) {
        int t = __shfl_up(incl, d, 64);
        if (lane >= d) incl += t;
    }
    __shared__ int ws[4];
    if (lane == 63) ws[wid] = incl;
    __syncthreads();
    int wpre = 0;
    for (int ww = 0; ww < wid; ++ww) wpre += ws[ww];
    int e = wpre + incl - tsum;
#pragma unroll
    for (int k = 0; k < 4; ++k) { int i = base + k; if (i < n) off[i] = e; e += v[k]; }
    if (tid == 255) bsum[blockIdx.x] = wpre + incl;
}

// scanB: add scanned chunk prefixes; write sentinel off[n]=total.
__global__ __launch_bounds__(256) void k_scanB(
    int* __restrict__ off0, int* __restrict__ off1,
    const int* __restrict__ bsum, int n, int nchunk) {
    int arr = blockIdx.x >= nchunk;
    int c = blockIdx.x - (arr ? nchunk : 0);
    int* off = arr ? off1 : off0;
    const int* bs = bsum + (arr ? nchunk : 0);
    __shared__ int pre_s, tot_s;
    int tid = threadIdx.x;
    if (tid < 64) {
        int v = (tid < nchunk) ? bs[tid] : 0;
        int incl = v;
#pragma unroll
        for (int d = 1; d < 64; d <<= 1) {
            int t = __shfl_up(incl, d, 64);
            if (tid >= d) incl += t;
        }
        if (tid == c) pre_s = incl - v;
        if (tid == nchunk - 1) tot_s = incl;
    }
    __syncthreads();
    int pre = pre_s;
    int base = c * 1024 + tid * 4;
#pragma unroll
    for (int k = 0; k < 4; ++k) {
        int i = base + k;
        if (i < n) off[i] += pre;
    }
    if (c == 0 && tid == 0) off[n] = tot_s;
}

// Binned placement at LDS-private cursors (block-private contiguous sub-regions).
__global__ __launch_bounds__(256) void k_bin(
    const int* __restrict__ ei, int nE, int nbuck,
    const int* __restrict__ curD, const int* __restrict__ curS,
    unsigned* __restrict__ binnedD, unsigned* __restrict__ binnedS) {
    __shared__ int cD[256], cS[256];
    int tid = threadIdx.x;
    int hb = blockIdx.x;
    if (tid < nbuck) {
        cD[tid] = curD[tid * 256 + hb];
        cS[tid] = curS[tid * 256 + hb];
    }
    __syncthreads();
    int chunk = (nE + 255) >> 8;
    int lo = hb * chunk;
    int hi = lo + chunk; if (hi > nE) hi = nE;
    for (int e = lo + tid; e < hi; e += 256) {
        int s = ei[e], d = ei[nE + e];
        unsigned pk = (unsigned)s | ((unsigned)d << 16);
        int p = atomicAdd(&cD[d >> 8], 1);
        binnedD[p] = pk;
        int q = atomicAdd(&cS[s >> 8], 1);
        binnedS[q] = pk;
    }
}

// Fine sort within each (bucket, dir): LDS count -> scan -> staged placement.
__global__ __launch_bounds__(256) void k_fine(
    const unsigned* __restrict__ binnedD, const unsigned* __restrict__ binnedS,
    const int* __restrict__ curD, const int* __restrict__ curS,
    int* __restrict__ off_dst, int* __restrict__ off_src,
    unsigned short* __restrict__ adj_dst, unsigned short* __restrict__ adj_src,
    int nE, int nN, int nbuck) {
    int bk = blockIdx.x;
    int dd = 0;
    if (bk >= nbuck) { dd = 1; bk -= nbuck; }
    const unsigned* binned = dd ? binnedS : binnedD;
    const int* cur = dd ? curS : curD;
    int* off = dd ? off_src : off_dst;
    unsigned short* adj = dd ? adj_src : adj_dst;
    __shared__ int ncnt[256];
    __shared__ int cur2[256];
    __shared__ unsigned short stage[FCAP];
    int tid = threadIdx.x;
    ncnt[tid] = 0;
    __syncthreads();
    int base = cur[bk * 256];
    int endp = cur[(bk + 1) * 256];
    int cntE = endp - base;
    int n0 = bk << 8;
    for (int i = tid; i < cntE; i += 256) {
        unsigned pk = binned[base + i];
        int key = dd ? (int)(pk & 0xFFFFu) : (int)(pk >> 16);
        atomicAdd(&ncnt[key - n0], 1);
    }
    __syncthreads();
    if (tid < 64) {
        int i4 = tid << 2;
        int v0 = ncnt[i4], v1 = ncnt[i4 + 1], v2 = ncnt[i4 + 2], v3 = ncnt[i4 + 3];
        int tsum = v0 + v1 + v2 + v3;
        int incl = tsum;
#pragma unroll
        for (int d = 1; d < 64; d <<= 1) {
            int t = __shfl_up(incl, d, 64);
            if (tid >= d) incl += t;
        }
        int excl = incl - tsum;
        ncnt[i4] = excl;
        ncnt[i4 + 1] = excl + v0;
        ncnt[i4 + 2] = excl + v0 + v1;
        ncnt[i4 + 3] = excl + v0 + v1 + v2;
    }
    __syncthreads();
    cur2[tid] = ncnt[tid];
    int node = n0 + tid;
    if (node < nN) off[node] = base + ncnt[tid];
    if (bk == nbuck - 1 && tid == 0) off[nN] = nE;
    __syncthreads();
    for (int i = tid; i < cntE; i += 256) {
        unsigned pk = binned[base + i];
        int key = dd ? (int)(pk & 0xFFFFu) : (int)(pk >> 16);
        int oth = dd ? (int)(pk >> 16) : (int)(pk & 0xFFFFu);
        int pos = atomicAdd(&cur2[key - n0], 1);
        if (pos < FCAP) stage[pos] = (unsigned short)oth;
        else adj[base + pos] = (unsigned short)oth;
    }
    __syncthreads();
    int lim = cntE < FCAP ? cntE : FCAP;
    for (int i = tid; i < lim; i += 256) adj[base + i] = stage[i];
}

// Gather: 16-lane group per node; lane fl holds features 4fl..4fl+3.
__global__ __launch_bounds__(256) void k_gather(
    const half_t* __restrict__ P1, const half_t* __restrict__ P2,
    const half_t* __restrict__ Q1, const half_t* __restrict__ Q2,
    const int* __restrict__ off1, const unsigned short* __restrict__ adj1,
    const int* __restrict__ off2, const unsigned short* __restrict__ adj2,
    half_t* __restrict__ agg1, half_t* __restrict__ agg2,
    float* __restrict__ amp1, float* __restrict__ ramp1,
    float* __restrict__ amp2, float* __restrict__ ramp2, int nN, int nE) {
    int tid = threadIdx.x;
    const int lane = tid & 63;
    const int g = lane >> 4;         // node slot within wave (0..3)
    const int fl = lane & 15;        // feature quad
    const int fl8 = fl << 3;
    int w4 = (blockIdx.x * 256 + tid) >> 6;
    int wstride = (gridDim.x * 256) >> 6;
    int ngroups = (nN + 3) >> 2;
#pragma unroll
    for (int d = 0; d < 2; ++d) {
        const char* Pc = (const char*)(d ? P2 : P1);
        const char* Qc = (const char*)(d ? Q2 : Q1);
        const int* off = d ? off2 : off1;
        const unsigned short* adj = d ? adj2 : adj1;
        char* aggc = (char*)(d ? agg2 : agg1);
        float* ampA = d ? amp2 : amp1;
        float* rampA = d ? ramp2 : ramp1;
        for (int gi = w4; gi < ngroups; gi += wstride) {
            int node = gi * 4 + g;
            bool act = node < nN;
            int nodec = act ? node : (nN - 1);
            int beg = off[nodec], end = off[nodec + 1];
            int cnt = end - beg;
            half2v s01 = {(half_t)0, (half_t)0}, s23 = {(half_t)0, (half_t)0};
            half2v ss01 = {(half_t)0, (half_t)0}, ss23 = {(half_t)0, (half_t)0};
            unsigned mn0 = 0x7C007C00u, mn1 = 0x7C007C00u;
            unsigned mx0 = 0xFC00FC00u, mx1 = 0xFC00FC00u;
            int j = beg;
            for (; j + 4 <= end; j += 4) {
                int n0 = adj[j + 0];
                int n1 = adj[j + 1];
                int n2 = adj[j + 2];
                int n3 = adj[j + 3];
                uint2 u0 = *(const uint2*)(Pc + n0 * 128 + fl8);
                uint2 u1 = *(const uint2*)(Pc + n1 * 128 + fl8);
                uint2 u2 = *(const uint2*)(Pc + n2 * 128 + fl8);
                uint2 u3 = *(const uint2*)(Pc + n3 * 128 + fl8);
                half2v a0 = u2h(u0.x), a1 = u2h(u0.y);
                half2v b0 = u2h(u1.x), b1 = u2h(u1.y);
                half2v c0 = u2h(u2.x), c1 = u2h(u2.y);
                half2v e0 = u2h(u3.x), e1 = u2h(u3.y);
                s01 += (a0 + b0) + (c0 + e0);
                s23 += (a1 + b1) + (c1 + e1);
                ss01 += a0 * a0; ss23 += a1 * a1;
                ss01 += b0 * b0; ss23 += b1 * b1;
                ss01 += c0 * c0; ss23 += c1 * c1;
                ss01 += e0 * e0; ss23 += e1 * e1;
                mn0 = pkmin(mn0, pkmin(pkmin(u0.x, u1.x), pkmin(u2.x, u3.x)));
                mn1 = pkmin(mn1, pkmin(pkmin(u0.y, u1.y), pkmin(u2.y, u3.y)));
                mx0 = pkmax(mx0, pkmax(pkmax(u0.x, u1.x), pkmax(u2.x, u3.x)));
                mx1 = pkmax(mx1, pkmax(pkmax(u0.y, u1.y), pkmax(u2.y, u3.y)));
            }
            for (; j < end; ++j) {
                int n0 = adj[j];
                uint2 u0 = *(const uint2*)(Pc + n0 * 128 + fl8);
                half2v a0 = u2h(u0.x), a1 = u2h(u0.y);
                s01 += a0; s23 += a1;
                ss01 += a0 * a0; ss23 += a1 * a1;
                mn0 = pkmin(mn0, u0.x); mn1 = pkmin(mn1, u0.y);
                mx0 = pkmax(mx0, u0.x); mx1 = pkmax(mx1, u0.y);
            }
            float deg = (cnt > 0) ? (float)cnt : 1.0f;
            float inv = 1.0f / deg;
            float se0 = (float)s01[0], se1 = (float)s01[1];
            float se2 = (float)s23[0], se3 = (float)s23[1];
            float sq0 = (float)ss01[0], sq1 = (float)ss01[1];
            float sq2 = (float)ss23[0], sq3 = (float)ss23[1];
            float me0 = se0 * inv, me1 = se1 * inv, me2 = se2 * inv, me3 = se3 * inv;
            float st0 = sqrtf(fmaxf(fmaf(-me0, me0, sq0 * inv), 0.f) + 1e-5f);
            float st1 = sqrtf(fmaxf(fmaf(-me1, me1, sq1 * inv), 0.f) + 1e-5f);
            float st2 = sqrtf(fmaxf(fmaf(-me2, me2, sq2 * inv), 0.f) + 1e-5f);
            float st3 = sqrtf(fmaxf(fmaf(-me3, me3, sq3 * inv), 0.f) + 1e-5f);
            uint2 qu = *(const uint2*)(Qc + nodec * 128 + fl8);
            half2v q01 = u2h(qu.x), q23 = u2h(qu.y);
            half2v hm01, hm23, hl01, hl23, hh01, hh23;
            if (cnt > 0) {
                hm01 = q01 + pkrtz(me0, me1);
                hm23 = q23 + pkrtz(me2, me3);
                hl01 = q01 + u2h(mn0); hl23 = q23 + u2h(mn1);
                hh01 = q01 + u2h(mx0); hh23 = q23 + u2h(mx1);
            } else {
                half2v z = {(half_t)0, (half_t)0};
                hm01 = z; hm23 = z; hl01 = z; hl23 = z; hh01 = z; hh23 = z;
            }
            half2v hs01 = pkrtz(st0, st1);
            half2v hs23 = pkrtz(st2, st3);
            if (act) {
                char* ab = aggc + (size_t)node * 512 + (fl >> 2) * 128 + (fl & 3) * 8;
                uint2 w0; w0.x = (unsigned)h2i(hm01); w0.y = (unsigned)h2i(hm23);
                uint2 w1; w1.x = (unsigned)h2i(hl01); w1.y = (unsigned)h2i(hl23);
                uint2 w2; w2.x = (unsigned)h2i(hh01); w2.y = (unsigned)h2i(hh23);
                uint2 w3; w3.x = (unsigned)h2i(hs01); w3.y = (unsigned)h2i(hs23);
                *(uint2*)(ab)      = w0;
                *(uint2*)(ab + 32) = w1;
                *(uint2*)(ab + 64) = w2;
                *(uint2*)(ab + 96) = w3;
                if (fl == 0) {
                    float ampv = __log2f(deg + 1.0f) * 0.24465054f;  // 1/log2(17)
                    ampA[node] = ampv;
                    rampA[node] = 1.0f / ampv;
                }
            }
        }
    }
}

// Persistent MFMA pass, swapped operands. Batched prefetch: all 16 agg fragments,
// xh, amp/ramp issued up-front per tile (deep MLP); per-direction double-buffered
// wave-private LDS bounce so the two directions' MFMA phases overlap.
__global__ __launch_bounds__(256, 2) void k_c(
    const half_t* __restrict__ xh,
    const half_t* __restrict__ agg1, const half_t* __restrict__ agg2,
    const float* __restrict__ amp1, const float* __restrict__ ramp1,
    const float* __restrict__ amp2, const float* __restrict__ ramp2,
    const half_t* __restrict__ WLg, const half_t* __restrict__ WfinT,
    const float* __restrict__ bfin, float* __restrict__ out, int nN) {
    __shared__ half_t WLs[24 * 16 * 72];
    __shared__ half_t osb[8 * 16 * 72];   // [wave][dir] double-buffered oT
    int tid = threadIdx.x;
    {
        const uint4* src = (const uint4*)WLg;
        uint4* dst = (uint4*)WLs;
        for (int i = tid; i < (24 * 16 * 72) / 8; i += 256) dst[i] = src[i];
    }
    __syncthreads();
    int w = tid >> 6, lane = tid & 63;
    int l15 = lane & 15, g4 = lane >> 4;
    half8 wfr[4][6];
#pragma unroll
    for (int ct = 0; ct < 4; ++ct)
#pragma unroll
        for (int kk = 0; kk < 6; ++kk)
            wfr[ct][kk] = *(const half8*)(WfinT + (ct * 16 + l15) * 192 + kk * 32 + g4 * 8);
    float4 bf4[4];
#pragma unroll
    for (int ct = 0; ct < 4; ++ct)
        bf4[ct] = *(const float4*)(bfin + ct * 16 + g4 * 4);
    int nwaves = gridDim.x * 4;
    int wgid = blockIdx.x * 4 + w;
    int ntiles = (nN + 15) >> 4;
    for (int tile = wgid; tile < ntiles; tile += nwaves) {
        int nrow = (tile << 4) + l15;
        int nrowc = (nrow < nN) ? nrow : (nN - 1);
        // ---- batched prefetch: issue ALL tile loads before any compute ----
        const half_t* a1p = agg1 + (size_t)nrowc * 256;
        const half_t* a2p = agg2 + (size_t)nrowc * 256;
        half8 agf[2][8];
#pragma unroll
        for (int t = 0; t < 4; ++t) {
            agf[0][t * 2]     = *(const half8*)(a1p + t * 64 + g4 * 8);
            agf[0][t * 2 + 1] = *(const half8*)(a1p + t * 64 + 32 + g4 * 8);
            agf[1][t * 2]     = *(const half8*)(a2p + t * 64 + g4 * 8);
            agf[1][t * 2 + 1] = *(const half8*)(a2p + t * 64 + 32 + g4 * 8);
        }
        half8 xbf[2];
#pragma unroll
        for (int ks = 0; ks < 2; ++ks)
            xbf[ks] = *(const half8*)(xh + (size_t)nrowc * 64 + ks * 32 + g4 * 8);
        float ampv[2], rampv[2];
        ampv[0] = amp1[nrowc]; rampv[0] = ramp1[nrowc];
        ampv[1] = amp2[nrowc]; rampv[1] = ramp2[nrowc];
        // ---- compute ----
        f32x4 accY[4] = {{0,0,0,0},{0,0,0,0},{0,0,0,0},{0,0,0,0}};
#pragma unroll
        for (int d = 0; d < 2; ++d) {
            half_t* ow = osb + (w * 2 + d) * (16 * 72) + l15 * 72;
#pragma unroll
            for (int t = 0; t < 4; ++t) {
                half8 b0 = agf[d][t * 2];
                half8 b1 = agf[d][t * 2 + 1];
                const half_t* wb = WLs + ((d * 12 + t * 3) * 16 + l15) * 72 + g4 * 8;
                half8 aA0 = *(const half8*)(wb);
                half8 aA1 = *(const half8*)(wb + 32);
                half8 aB0 = *(const half8*)(wb + 16 * 72);
                half8 aB1 = *(const half8*)(wb + 16 * 72 + 32);
                half8 aE0 = *(const half8*)(wb + 32 * 72);
                half8 aE1 = *(const half8*)(wb + 32 * 72 + 32);
                f32x4 zA = {0,0,0,0}, zB = {0,0,0,0}, zE = {0,0,0,0};
                zA = __builtin_amdgcn_mfma_f32_16x16x32_f16(aA0, b0, zA, 0, 0, 0);
                zA = __builtin_amdgcn_mfma_f32_16x16x32_f16(aA1, b1, zA, 0, 0, 0);
                zB = __builtin_amdgcn_mfma_f32_16x16x32_f16(aB0, b0, zB, 0, 0, 0);
                zB = __builtin_amdgcn_mfma_f32_16x16x32_f16(aB1, b1, zB, 0, 0, 0);
                zE = __builtin_amdgcn_mfma_f32_16x16x32_f16(aE0, b0, zE, 0, 0, 0);
                zE = __builtin_amdgcn_mfma_f32_16x16x32_f16(aE1, b1, zE, 0, 0, 0);
                float o0 = zA[0] + ampv[d] * zB[0] + rampv[d] * zE[0];
                float o1 = zA[1] + ampv[d] * zB[1] + rampv[d] * zE[1];
                float o2 = zA[2] + ampv[d] * zB[2] + rampv[d] * zE[2];
                float o3 = zA[3] + ampv[d] * zB[3] + rampv[d] * zE[3];
                half2v p0; p0[0] = (half_t)o0; p0[1] = (half_t)o1;
                half2v p1; p1[0] = (half_t)o2; p1[1] = (half_t)o3;
                *(half2v*)(ow + t * 16 + g4 * 4) = p0;
                *(half2v*)(ow + t * 16 + g4 * 4 + 2) = p1;
            }
#pragma unroll
            for (int ks = 0; ks < 2; ++ks) {
                half8 ob = *(const half8*)(ow + ks * 32 + g4 * 8);
#pragma unroll
                for (int ct = 0; ct < 4; ++ct)
                    accY[ct] = __builtin_amdgcn_mfma_f32_16x16x32_f16(wfr[ct][d * 2 + ks], ob, accY[ct], 0, 0, 0);
            }
        }
#pragma unroll
        for (int ks = 0; ks < 2; ++ks)
#pragma unroll
            for (int ct = 0; ct < 4; ++ct)
                accY[ct] = __builtin_amdgcn_mfma_f32_16x16x32_f16(wfr[ct][4 + ks], xbf[ks], accY[ct], 0, 0, 0);
        if (nrow < nN) {
#pragma unroll
            for (int ct = 0; ct < 4; ++ct) {
                float4 st;
                st.x = accY[ct][0] + bf4[ct].x;
                st.y = accY[ct][1] + bf4[ct].y;
                st.z = accY[ct][2] + bf4[ct].z;
                st.w = accY[ct][3] + bf4[ct].w;
                *(float4*)(out + (size_t)nrow * 64 + ct * 16 + g4 * 4) = st;
            }
        }
    }
}

extern "C" void kernel_launch(void* const* d_in, const int* in_sizes, int n_in,
                              void* d_out, int out_size, void* d_ws, size_t ws_size,
                              hipStream_t stream) {
    const float* x      = (const float*)d_in[0];
    const int*   ei     = (const int*)d_in[1];
    const float* alpha  = (const float*)d_in[2];
    const float* Wself  = (const float*)d_in[3];
    const float* bself  = (const float*)d_in[4];
    const float* preW1  = (const float*)d_in[5];
    const float* preb1  = (const float*)d_in[6];
    const float* postW1 = (const float*)d_in[7];
    const float* postb1 = (const float*)d_in[8];
    const float* linW1  = (const float*)d_in[9];
    const float* linb1  = (const float*)d_in[10];
    const float* preW2  = (const float*)d_in[11];
    const float* preb2  = (const float*)d_in[12];
    const float* postW2 = (const float*)d_in[13];
    const float* postb2 = (const float*)d_in[14];
    const float* linW2  = (const float*)d_in[15];
    const float* linb2  = (const float*)d_in[16];
    float* out = (float*)d_out;
    const int nN = in_sizes[0] / 64;
    const int nE = in_sizes[1] / 2;
    const int nbuck = (nN + 255) >> 8;
    const int nH = nbuck * 256;
    const int nchunk = (nH + 1023) >> 10;

    char* w = (char*)d_ws;
    size_t ofs = 0;
    auto alloc = [&](size_t bytes) {
        char* p = w + ofs;
        ofs = (ofs + bytes + 255) & ~(size_t)255;
        return p;
    };
    half_t* P1   = (half_t*)alloc((size_t)nN * 64 * 2);
    half_t* P2   = (half_t*)alloc((size_t)nN * 64 * 2);
    half_t* Q1   = (half_t*)alloc((size_t)nN * 64 * 2);
    half_t* Q2   = (half_t*)alloc((size_t)nN * 64 * 2);
    half_t* xh   = (half_t*)alloc((size_t)nN * 64 * 2);
    half_t* agg1 = (half_t*)alloc((size_t)nN * 256 * 2);
    half_t* agg2 = (half_t*)alloc((size_t)nN * 256 * 2);
    float* amp1  = (float*)alloc((size_t)nN * 4);
    float* ramp1 = (float*)alloc((size_t)nN * 4);
    float* amp2  = (float*)alloc((size_t)nN * 4);
    float* ramp2 = (float*)alloc((size_t)nN * 4);
    half_t* WLg   = (half_t*)alloc(24 * 16 * 72 * 2);
    half_t* WfinT = (half_t*)alloc(64 * 192 * 2);
    float* bfin   = (float*)alloc(64 * 4);
    int* histD = (int*)alloc(256 * 256 * 4);
    int* histS = (int*)alloc(256 * 256 * 4);
    int* curD  = (int*)alloc((256 * 256 + 1) * 4);
    int* curS  = (int*)alloc((256 * 256 + 1) * 4);
    unsigned* binnedD = (unsigned*)alloc((size_t)nE * 4);
    unsigned* binnedS = (unsigned*)alloc((size_t)nE * 4);
    int* off_dst = (int*)alloc((size_t)(nN + 1) * 4);
    int* off_src = (int*)alloc((size_t)(nN + 1) * 4);
    unsigned short* adj_dst = (unsigned short*)alloc((size_t)nE * 2);
    unsigned short* adj_src = (unsigned short*)alloc((size_t)nE * 2);
    int* bsum = (int*)alloc(2 * 64 * 4);

    k_pre<<<1088, 256, 0, stream>>>(ei, nE, nN, histD, histS,
                                    postW1, postW2, linW1, linW2, Wself, bself,
                                    linb1, linb2, postb1, postb2, alpha,
                                    WLg, WfinT, bfin,
                                    x, preW1, preW2, preb1, preb2,
                                    P1, P2, Q1, Q2, xh);
    k_scanA<<<2 * nchunk, 256, 0, stream>>>(histD, histS, curD, curS, bsum, nH, nchunk);
    k_scanB<<<2 * nchunk, 256, 0, stream>>>(curD, curS, bsum, nH, nchunk);
    k_bin<<<256, 256, 0, stream>>>(ei, nE, nbuck, curD, curS, binnedD, binnedS);
    k_fine<<<2 * nbuck, 256, 0, stream>>>(binnedD, binnedS, curD, curS,
                                          off_dst, off_src, adj_dst, adj_src,
                                          nE, nN, nbuck);
    k_gather<<<2048, 256, 0, stream>>>(P1, P2, Q1, Q2, off_dst, adj_dst, off_src, adj_src,
                                       agg1, agg2, amp1, ramp1, amp2, ramp2, nN, nE);
    k_c<<<512, 256, 0, stream>>>(xh, agg1, agg2, amp1, ramp1, amp2, ramp2,
                                 WLg, WfinT, bfin, out, nN);
}

// Round 12
// 127.372 us; speedup vs baseline: 1.1752x; 1.1752x over previous
//
#include <hip/hip_runtime.h>
#include <math.h>

// DirPNAConv: N=50000, E=800000, D=64, T=4, FI=FO=16.
// m[e] = Q[recv] + P[send] -> gather-stats of P + per-node Q shift (Q precomputed f16).
// Tower block-diagonality: post layer = per-tower K=64 GEMMs; x@Wx and postb folded
// through lin into Wfin/bfin. k_c: batched-prefetch tile loads (launch_bounds(256,1)
// so the batch fits in VGPRs without spill), oT = W@aggT per tower (swapped
// operands), single-buffer wave-private LDS bounce (64.5KB -> 2 blocks/CU),
// y^T = WfinT@[o1,o2,x]^T. Graph build: atomic-free counting sort.
// Gather: 16-lane-group-per-node, packed f16 accumulation.

typedef _Float16 half_t;
typedef __attribute__((ext_vector_type(8))) _Float16 half8;
typedef __attribute__((ext_vector_type(2))) _Float16 half2v;
typedef __attribute__((ext_vector_type(4))) float f32x4;

#define FCAP 12288

static __device__ __forceinline__ unsigned pkmin(unsigned a, unsigned b) {
    unsigned r;
    asm("v_pk_min_f16 %0, %1, %2" : "=v"(r) : "v"(a), "v"(b));
    return r;
}
static __device__ __forceinline__ unsigned pkmax(unsigned a, unsigned b) {
    unsigned r;
    asm("v_pk_max_f16 %0, %1, %2" : "=v"(r) : "v"(a), "v"(b));
    return r;
}
static __device__ __forceinline__ int h2i(half2v h) { return __builtin_bit_cast(int, h); }
static __device__ __forceinline__ half2v u2h(unsigned i) { return __builtin_bit_cast(half2v, i); }
static __device__ __forceinline__ half2v pkrtz(float a, float b) {
    return __builtin_bit_cast(half2v, __builtin_amdgcn_cvt_pkrtz(a, b));
}

// ---- fused: LDS edge histogram | weight prep | P,Q,xh projection ----
__global__ __launch_bounds__(256) void k_pre(
    const int* __restrict__ ei, int nE, int nN,
    int* __restrict__ histD, int* __restrict__ histS,
    const float* __restrict__ postW1, const float* __restrict__ postW2,
    const float* __restrict__ linW1, const float* __restrict__ linW2,
    const float* __restrict__ Wself, const float* __restrict__ bself,
    const float* __restrict__ linb1, const float* __restrict__ linb2,
    const float* __restrict__ postb1, const float* __restrict__ postb2,
    const float* __restrict__ alpha,
    half_t* __restrict__ WLg, half_t* __restrict__ WfinTg, float* __restrict__ bfin,
    const float* __restrict__ x,
    const float* __restrict__ preW1, const float* __restrict__ preW2,
    const float* __restrict__ preb1, const float* __restrict__ preb2,
    half_t* __restrict__ P1, half_t* __restrict__ P2,
    half_t* __restrict__ Q1, half_t* __restrict__ Q2, half_t* __restrict__ xh) {
    int tid = threadIdx.x;
    int b = blockIdx.x;
    if (b < 256) {
        __shared__ int hD[256], hS[256];
        hD[tid] = 0; hS[tid] = 0;
        __syncthreads();
        int chunk = (nE + 255) >> 8;
        int lo = b * chunk;
        int hi = lo + chunk; if (hi > nE) hi = nE;
        for (int e = lo + tid; e < hi; e += 256) {
            int s = ei[e], d = ei[nE + e];
            atomicAdd(&hD[d >> 8], 1);
            atomicAdd(&hS[s >> 8], 1);
        }
        __syncthreads();
        histD[tid * 256 + b] = hD[tid];
        histS[tid * 256 + b] = hS[tid];
    } else if (b < 320) {
        const float a = alpha[0];
        int id = (b - 256) * 256 + tid;
        const int stride = 64 * 256;
        for (int i = id; i < 24 * 16 * 72; i += stride) {
            int m = i / (16 * 72);
            int r = i % (16 * 72);
            int go = r / 72, k = r % 72;
            int d = m / 12, t = (m / 3) % 4, mat = m % 3;
            float v = 0.f;
            if (k < 64) {
                int stat = k >> 4, g = k & 15;
                int basep = (mat == 0) ? 1 : (mat == 1 ? 5 : 9);
                const float* pw = d ? postW2 : postW1;
                v = pw[t * 3328 + ((basep + stat) * 16 + g) * 16 + go];
            }
            WLg[i] = (half_t)v;
        }
        for (int i = id; i < 64 * 192; i += stride) {
            int o = i / 192, k = i % 192;
            float v;
            if (k < 64)       v = (1.f - a) * linW1[k * 64 + o];
            else if (k < 128) v = a * linW2[(k - 64) * 64 + o];
            else {
                int kx = k - 128, t = kx >> 4, f = kx & 15;
                v = Wself[kx * 64 + o];
                float s1 = 0.f, s2 = 0.f;
                for (int go = 0; go < 16; ++go) {
                    s1 += postW1[t * 3328 + f * 16 + go] * linW1[(t * 16 + go) * 64 + o];
                    s2 += postW2[t * 3328 + f * 16 + go] * linW2[(t * 16 + go) * 64 + o];
                }
                v += (1.f - a) * s1 + a * s2;
            }
            WfinTg[i] = (half_t)v;
        }
        for (int i = id; i < 64; i += stride) {
            float v = bself[i] + (1.f - a) * linb1[i] + a * linb2[i];
            for (int j = 0; j < 64; ++j)
                v += (1.f - a) * postb1[j] * linW1[j * 64 + i]
                   + a * postb2[j] * linW2[j * 64 + i];
            bfin[i] = v;
        }
    } else {
        int vb = b - 320;
        const int lane = tid & 63;
        const int t = lane >> 4, g = lane & 15;
        const int base = t << 4;
        float wsP1[16], wsP2[16], wsQ1[16], wsQ2[16];
#pragma unroll
        for (int f = 0; f < 16; ++f) {
            wsP1[f] = preW1[t * 512 + (16 + f) * 16 + g];
            wsP2[f] = preW2[t * 512 + (16 + f) * 16 + g];
            wsQ1[f] = preW1[t * 512 + f * 16 + g];
            wsQ2[f] = preW2[t * 512 + f * 16 + g];
        }
        const float pb1 = preb1[lane], pb2 = preb2[lane];
        int node = (vb * 256 + tid) >> 6;
        const int stride = (768 * 256) >> 6;
        for (; node < nN; node += stride) {
            float xv = x[(size_t)node * 64 + lane];
            float p1 = 0.f, p2 = 0.f, q1 = pb1, q2 = pb2;
#pragma unroll
            for (int f = 0; f < 16; ++f) {
                float v = __shfl(xv, base + f, 64);
                p1 = fmaf(v, wsP1[f], p1);
                p2 = fmaf(v, wsP2[f], p2);
                q1 = fmaf(v, wsQ1[f], q1);
                q2 = fmaf(v, wsQ2[f], q2);
            }
            size_t o = (size_t)node * 64 + lane;
            P1[o] = (half_t)p1;
            P2[o] = (half_t)p2;
            Q1[o] = (half_t)q1;
            Q2[o] = (half_t)q2;
            xh[o] = (half_t)xv;
        }
    }
}

// Two-level scan. scanA: per-1024 chunk local exclusive scan + chunk sums.
__global__ __launch_bounds__(256) void k_scanA(
    const int* __restrict__ cnt0, const int* __restrict__ cnt1,
    int* __restrict__ off0, int* __restrict__ off1,
    int* __restrict__ bsum, int n, int nchunk) {
    int arr = blockIdx.x >= nchunk;
    int c = blockIdx.x - (arr ? nchunk : 0);
    const int* cnt = arr ? cnt1 : cnt0;
    int* off = arr ? off1 : off0;
    int tid = threadIdx.x;
    int base = c * 1024 + tid * 4;
    int v[4];
#pragma unroll
    for (int k = 0; k < 4; ++k) { int i = base + k; v[k] = (i < n) ? cnt[i] : 0; }
    int tsum = v[0] + v[1] + v[2] + v[3];
    int lane = tid & 63, wid = tid >> 6;
    int incl = tsum;
#pragma unroll
    for (int d = 1; d < 64; d <<= 1) {
        int t = __shfl_up(incl, d, 64);
        if (lane >= d) incl += t;
    }
    __shared__ int ws[4];
    if (lane == 63) ws[wid] = incl;
    __syncthreads();
    int wpre = 0;
    for (int ww = 0; ww < wid; ++ww) wpre += ws[ww];
    int e = wpre + incl - tsum;
#pragma unroll
    for (int k = 0; k < 4; ++k) { int i = base + k; if (i < n) off[i] = e; e += v[k]; }
    if (tid == 255) bsum[blockIdx.x] = wpre + incl;
}

// scanB: add scanned chunk prefixes; write sentinel off[n]=total.
__global__ __launch_bounds__(256) void k_scanB(
    int* __restrict__ off0, int* __restrict__ off1,
    const int* __restrict__ bsum, int n, int nchunk) {
    int arr = blockIdx.x >= nchunk;
    int c = blockIdx.x - (arr ? nchunk : 0);
    int* off = arr ? off1 : off0;
    const int* bs = bsum + (arr ? nchunk : 0);
    __shared__ int pre_s, tot_s;
    int tid = threadIdx.x;
    if (tid < 64) {
        int v = (tid < nchunk) ? bs[tid] : 0;
        int incl = v;
#pragma unroll
        for (int d = 1; d < 64; d <<= 1) {
            int t = __shfl_up(incl, d, 64);
            if (tid >= d) incl += t;
        }
        if (tid == c) pre_s = incl - v;
        if (tid == nchunk - 1) tot_s = incl;
    }
    __syncthreads();
    int pre = pre_s;
    int base = c * 1024 + tid * 4;
#pragma unroll
    for (int k = 0; k < 4; ++k) {
        int i = base + k;
        if (i < n) off[i] += pre;
    }
    if (c == 0 && tid == 0) off[n] = tot_s;
}

// Binned placement at LDS-private cursors (block-private contiguous sub-regions).
__global__ __launch_bounds__(256) void k_bin(
    const int* __restrict__ ei, int nE, int nbuck,
    const int* __restrict__ curD, const int* __restrict__ curS,
    unsigned* __restrict__ binnedD, unsigned* __restrict__ binnedS) {
    __shared__ int cD[256], cS[256];
    int tid = threadIdx.x;
    int hb = blockIdx.x;
    if (tid < nbuck) {
        cD[tid] = curD[tid * 256 + hb];
        cS[tid] = curS[tid * 256 + hb];
    }
    __syncthreads();
    int chunk = (nE + 255) >> 8;
    int lo = hb * chunk;
    int hi = lo + chunk; if (hi > nE) hi = nE;
    for (int e = lo + tid; e < hi; e += 256) {
        int s = ei[e], d = ei[nE + e];
        unsigned pk = (unsigned)s | ((unsigned)d << 16);
        int p = atomicAdd(&cD[d >> 8], 1);
        binnedD[p] = pk;
        int q = atomicAdd(&cS[s >> 8], 1);
        binnedS[q] = pk;
    }
}

// Fine sort within each (bucket, dir): LDS count -> scan -> staged placement.
__global__ __launch_bounds__(256) void k_fine(
    const unsigned* __restrict__ binnedD, const unsigned* __restrict__ binnedS,
    const int* __restrict__ curD, const int* __restrict__ curS,
    int* __restrict__ off_dst, int* __restrict__ off_src,
    unsigned short* __restrict__ adj_dst, unsigned short* __restrict__ adj_src,
    int nE, int nN, int nbuck) {
    int bk = blockIdx.x;
    int dd = 0;
    if (bk >= nbuck) { dd = 1; bk -= nbuck; }
    const unsigned* binned = dd ? binnedS : binnedD;
    const int* cur = dd ? curS : curD;
    int* off = dd ? off_src : off_dst;
    unsigned short* adj = dd ? adj_src : adj_dst;
    __shared__ int ncnt[256];
    __shared__ int cur2[256];
    __shared__ unsigned short stage[FCAP];
    int tid = threadIdx.x;
    ncnt[tid] = 0;
    __syncthreads();
    int base = cur[bk * 256];
    int endp = cur[(bk + 1) * 256];
    int cntE = endp - base;
    int n0 = bk << 8;
    for (int i = tid; i < cntE; i += 256) {
        unsigned pk = binned[base + i];
        int key = dd ? (int)(pk & 0xFFFFu) : (int)(pk >> 16);
        atomicAdd(&ncnt[key - n0], 1);
    }
    __syncthreads();
    if (tid < 64) {
        int i4 = tid << 2;
        int v0 = ncnt[i4], v1 = ncnt[i4 + 1], v2 = ncnt[i4 + 2], v3 = ncnt[i4 + 3];
        int tsum = v0 + v1 + v2 + v3;
        int incl = tsum;
#pragma unroll
        for (int d = 1; d < 64; d <<= 1) {
            int t = __shfl_up(incl, d, 64);
            if (tid >= d) incl += t;
        }
        int excl = incl - tsum;
        ncnt[i4] = excl;
        ncnt[i4 + 1] = excl + v0;
        ncnt[i4 + 2] = excl + v0 + v1;
        ncnt[i4 + 3] = excl + v0 + v1 + v2;
    }
    __syncthreads();
    cur2[tid] = ncnt[tid];
    int node = n0 + tid;
    if (node < nN) off[node] = base + ncnt[tid];
    if (bk == nbuck - 1 && tid == 0) off[nN] = nE;
    __syncthreads();
    for (int i = tid; i < cntE; i += 256) {
        unsigned pk = binned[base + i];
        int key = dd ? (int)(pk & 0xFFFFu) : (int)(pk >> 16);
        int oth = dd ? (int)(pk >> 16) : (int)(pk & 0xFFFFu);
        int pos = atomicAdd(&cur2[key - n0], 1);
        if (pos < FCAP) stage[pos] = (unsigned short)oth;
        else adj[base + pos] = (unsigned short)oth;
    }
    __syncthreads();
    int lim = cntE < FCAP ? cntE : FCAP;
    for (int i = tid; i < lim; i += 256) adj[base + i] = stage[i];
}

// Gather: 16-lane group per node; lane fl holds features 4fl..4fl+3.
__global__ __launch_bounds__(256) void k_gather(
    const half_t* __restrict__ P1, const half_t* __restrict__ P2,
    const half_t* __restrict__ Q1, const half_t* __restrict__ Q2,
    const int* __restrict__ off1, const unsigned short* __restrict__ adj1,
    const int* __restrict__ off2, const unsigned short* __restrict__ adj2,
    half_t* __restrict__ agg1, half_t* __restrict__ agg2,
    float* __restrict__ amp1, float* __restrict__ ramp1,
    float* __restrict__ amp2, float* __restrict__ ramp2, int nN, int nE) {
    int tid = threadIdx.x;
    const int lane = tid & 63;
    const int g = lane >> 4;         // node slot within wave (0..3)
    const int fl = lane & 15;        // feature quad
    const int fl8 = fl << 3;
    int w4 = (blockIdx.x * 256 + tid) >> 6;
    int wstride = (gridDim.x * 256) >> 6;
    int ngroups = (nN + 3) >> 2;
#pragma unroll
    for (int d = 0; d < 2; ++d) {
        const char* Pc = (const char*)(d ? P2 : P1);
        const char* Qc = (const char*)(d ? Q2 : Q1);
        const int* off = d ? off2 : off1;
        const unsigned short* adj = d ? adj2 : adj1;
        char* aggc = (char*)(d ? agg2 : agg1);
        float* ampA = d ? amp2 : amp1;
        float* rampA = d ? ramp2 : ramp1;
        for (int gi = w4; gi < ngroups; gi += wstride) {
            int node = gi * 4 + g;
            bool act = node < nN;
            int nodec = act ? node : (nN - 1);
            int beg = off[nodec], end = off[nodec + 1];
            int cnt = end - beg;
            half2v s01 = {(half_t)0, (half_t)0}, s23 = {(half_t)0, (half_t)0};
            half2v ss01 = {(half_t)0, (half_t)0}, ss23 = {(half_t)0, (half_t)0};
            unsigned mn0 = 0x7C007C00u, mn1 = 0x7C007C00u;
            unsigned mx0 = 0xFC00FC00u, mx1 = 0xFC00FC00u;
            int j = beg;
            for (; j + 4 <= end; j += 4) {
                int n0 = adj[j + 0];
                int n1 = adj[j + 1];
                int n2 = adj[j + 2];
                int n3 = adj[j + 3];
                uint2 u0 = *(const uint2*)(Pc + n0 * 128 + fl8);
                uint2 u1 = *(const uint2*)(Pc + n1 * 128 + fl8);
                uint2 u2 = *(const uint2*)(Pc + n2 * 128 + fl8);
                uint2 u3 = *(const uint2*)(Pc + n3 * 128 + fl8);
                half2v a0 = u2h(u0.x), a1 = u2h(u0.y);
                half2v b0 = u2h(u1.x), b1 = u2h(u1.y);
                half2v c0 = u2h(u2.x), c1 = u2h(u2.y);
                half2v e0 = u2h(u3.x), e1 = u2h(u3.y);
                s01 += (a0 + b0) + (c0 + e0);
                s23 += (a1 + b1) + (c1 + e1);
                ss01 += a0 * a0; ss23 += a1 * a1;
                ss01 += b0 * b0; ss23 += b1 * b1;
                ss01 += c0 * c0; ss23 += c1 * c1;
                ss01 += e0 * e0; ss23 += e1 * e1;
                mn0 = pkmin(mn0, pkmin(pkmin(u0.x, u1.x), pkmin(u2.x, u3.x)));
                mn1 = pkmin(mn1, pkmin(pkmin(u0.y, u1.y), pkmin(u2.y, u3.y)));
                mx0 = pkmax(mx0, pkmax(pkmax(u0.x, u1.x), pkmax(u2.x, u3.x)));
                mx1 = pkmax(mx1, pkmax(pkmax(u0.y, u1.y), pkmax(u2.y, u3.y)));
            }
            for (; j < end; ++j) {
                int n0 = adj[j];
                uint2 u0 = *(const uint2*)(Pc + n0 * 128 + fl8);
                half2v a0 = u2h(u0.x), a1 = u2h(u0.y);
                s01 += a0; s23 += a1;
                ss01 += a0 * a0; ss23 += a1 * a1;
                mn0 = pkmin(mn0, u0.x); mn1 = pkmin(mn1, u0.y);
                mx0 = pkmax(mx0, u0.x); mx1 = pkmax(mx1, u0.y);
            }
            float deg = (cnt > 0) ? (float)cnt : 1.0f;
            float inv = 1.0f / deg;
            float se0 = (float)s01[0], se1 = (float)s01[1];
            float se2 = (float)s23[0], se3 = (float)s23[1];
            float sq0 = (float)ss01[0], sq1 = (float)ss01[1];
            float sq2 = (float)ss23[0], sq3 = (float)ss23[1];
            float me0 = se0 * inv, me1 = se1 * inv, me2 = se2 * inv, me3 = se3 * inv;
            float st0 = sqrtf(fmaxf(fmaf(-me0, me0, sq0 * inv), 0.f) + 1e-5f);
            float st1 = sqrtf(fmaxf(fmaf(-me1, me1, sq1 * inv), 0.f) + 1e-5f);
            float st2 = sqrtf(fmaxf(fmaf(-me2, me2, sq2 * inv), 0.f) + 1e-5f);
            float st3 = sqrtf(fmaxf(fmaf(-me3, me3, sq3 * inv), 0.f) + 1e-5f);
            uint2 qu = *(const uint2*)(Qc + nodec * 128 + fl8);
            half2v q01 = u2h(qu.x), q23 = u2h(qu.y);
            half2v hm01, hm23, hl01, hl23, hh01, hh23;
            if (cnt > 0) {
                hm01 = q01 + pkrtz(me0, me1);
                hm23 = q23 + pkrtz(me2, me3);
                hl01 = q01 + u2h(mn0); hl23 = q23 + u2h(mn1);
                hh01 = q01 + u2h(mx0); hh23 = q23 + u2h(mx1);
            } else {
                half2v z = {(half_t)0, (half_t)0};
                hm01 = z; hm23 = z; hl01 = z; hl23 = z; hh01 = z; hh23 = z;
            }
            half2v hs01 = pkrtz(st0, st1);
            half2v hs23 = pkrtz(st2, st3);
            if (act) {
                char* ab = aggc + (size_t)node * 512 + (fl >> 2) * 128 + (fl & 3) * 8;
                uint2 w0; w0.x = (unsigned)h2i(hm01); w0.y = (unsigned)h2i(hm23);
                uint2 w1; w1.x = (unsigned)h2i(hl01); w1.y = (unsigned)h2i(hl23);
                uint2 w2; w2.x = (unsigned)h2i(hh01); w2.y = (unsigned)h2i(hh23);
                uint2 w3; w3.x = (unsigned)h2i(hs01); w3.y = (unsigned)h2i(hs23);
                *(uint2*)(ab)      = w0;
                *(uint2*)(ab + 32) = w1;
                *(uint2*)(ab + 64) = w2;
                *(uint2*)(ab + 96) = w3;
                if (fl == 0) {
                    float ampv = __log2f(deg + 1.0f) * 0.24465054f;  // 1/log2(17)
                    ampA[node] = ampv;
                    rampA[node] = 1.0f / ampv;
                }
            }
        }
    }
}

// Persistent MFMA pass, swapped operands. Batched prefetch (all 16 agg fragments
// + xh + amps per tile, ~200 VGPR; launch_bounds(256,1) to avoid the 128-VGPR
// spill) with single-buffer wave-private LDS bounce (64.5KB -> 2 blocks/CU).
__global__ __launch_bounds__(256, 1) void k_c(
    const half_t* __restrict__ xh,
    const half_t* __restrict__ agg1, const half_t* __restrict__ agg2,
    const float* __restrict__ amp1, const float* __restrict__ ramp1,
    const float* __restrict__ amp2, const float* __restrict__ ramp2,
    const half_t* __restrict__ WLg, const half_t* __restrict__ WfinT,
    const float* __restrict__ bfin, float* __restrict__ out, int nN) {
    __shared__ half_t WLs[24 * 16 * 72];
    __shared__ half_t osb[4 * 16 * 72];
    int tid = threadIdx.x;
    {
        const uint4* src = (const uint4*)WLg;
        uint4* dst = (uint4*)WLs;
        for (int i = tid; i < (24 * 16 * 72) / 8; i += 256) dst[i] = src[i];
    }
    __syncthreads();
    int w = tid >> 6, lane = tid & 63;
    int l15 = lane & 15, g4 = lane >> 4;
    half_t* ow = osb + w * (16 * 72) + l15 * 72;
    half8 wfr[4][6];
#pragma unroll
    for (int ct = 0; ct < 4; ++ct)
#pragma unroll
        for (int kk = 0; kk < 6; ++kk)
            wfr[ct][kk] = *(const half8*)(WfinT + (ct * 16 + l15) * 192 + kk * 32 + g4 * 8);
    float4 bf4[4];
#pragma unroll
    for (int ct = 0; ct < 4; ++ct)
        bf4[ct] = *(const float4*)(bfin + ct * 16 + g4 * 4);
    int nwaves = gridDim.x * 4;
    int wgid = blockIdx.x * 4 + w;
    int ntiles = (nN + 15) >> 4;
    for (int tile = wgid; tile < ntiles; tile += nwaves) {
        int nrow = (tile << 4) + l15;
        int nrowc = (nrow < nN) ? nrow : (nN - 1);
        // ---- batched prefetch: issue ALL tile loads before any compute ----
        const half_t* a1p = agg1 + (size_t)nrowc * 256;
        const half_t* a2p = agg2 + (size_t)nrowc * 256;
        half8 agf[2][8];
#pragma unroll
        for (int t = 0; t < 4; ++t) {
            agf[0][t * 2]     = *(const half8*)(a1p + t * 64 + g4 * 8);
            agf[0][t * 2 + 1] = *(const half8*)(a1p + t * 64 + 32 + g4 * 8);
            agf[1][t * 2]     = *(const half8*)(a2p + t * 64 + g4 * 8);
            agf[1][t * 2 + 1] = *(const half8*)(a2p + t * 64 + 32 + g4 * 8);
        }
        half8 xbf[2];
#pragma unroll
        for (int ks = 0; ks < 2; ++ks)
            xbf[ks] = *(const half8*)(xh + (size_t)nrowc * 64 + ks * 32 + g4 * 8);
        float ampv[2], rampv[2];
        ampv[0] = amp1[nrowc]; rampv[0] = ramp1[nrowc];
        ampv[1] = amp2[nrowc]; rampv[1] = ramp2[nrowc];
        // ---- compute ----
        f32x4 accY[4] = {{0,0,0,0},{0,0,0,0},{0,0,0,0},{0,0,0,0}};
#pragma unroll
        for (int d = 0; d < 2; ++d) {
#pragma unroll
            for (int t = 0; t < 4; ++t) {
                half8 b0 = agf[d][t * 2];
                half8 b1 = agf[d][t * 2 + 1];
                const half_t* wb = WLs + ((d * 12 + t * 3) * 16 + l15) * 72 + g4 * 8;
                half8 aA0 = *(const half8*)(wb);
                half8 aA1 = *(const half8*)(wb + 32);
                half8 aB0 = *(const half8*)(wb + 16 * 72);
                half8 aB1 = *(const half8*)(wb + 16 * 72 + 32);
                half8 aE0 = *(const half8*)(wb + 32 * 72);
                half8 aE1 = *(const half8*)(wb + 32 * 72 + 32);
                f32x4 zA = {0,0,0,0}, zB = {0,0,0,0}, zE = {0,0,0,0};
                zA = __builtin_amdgcn_mfma_f32_16x16x32_f16(aA0, b0, zA, 0, 0, 0);
                zA = __builtin_amdgcn_mfma_f32_16x16x32_f16(aA1, b1, zA, 0, 0, 0);
                zB = __builtin_amdgcn_mfma_f32_16x16x32_f16(aB0, b0, zB, 0, 0, 0);
                zB = __builtin_amdgcn_mfma_f32_16x16x32_f16(aB1, b1, zB, 0, 0, 0);
                zE = __builtin_amdgcn_mfma_f32_16x16x32_f16(aE0, b0, zE, 0, 0, 0);
                zE = __builtin_amdgcn_mfma_f32_16x16x32_f16(aE1, b1, zE, 0, 0, 0);
                float o0 = zA[0] + ampv[d] * zB[0] + rampv[d] * zE[0];
                float o1 = zA[1] + ampv[d] * zB[1] + rampv[d] * zE[1];
                float o2 = zA[2] + ampv[d] * zB[2] + rampv[d] * zE[2];
                float o3 = zA[3] + ampv[d] * zB[3] + rampv[d] * zE[3];
                half2v p0; p0[0] = (half_t)o0; p0[1] = (half_t)o1;
                half2v p1; p1[0] = (half_t)o2; p1[1] = (half_t)o3;
                *(half2v*)(ow + t * 16 + g4 * 4) = p0;
                *(half2v*)(ow + t * 16 + g4 * 4 + 2) = p1;
            }
#pragma unroll
            for (int ks = 0; ks < 2; ++ks) {
                half8 ob = *(const half8*)(ow + ks * 32 + g4 * 8);
#pragma unroll
                for (int ct = 0; ct < 4; ++ct)
                    accY[ct] = __builtin_amdgcn_mfma_f32_16x16x32_f16(wfr[ct][d * 2 + ks], ob, accY[ct], 0, 0, 0);
            }
        }
#pragma unroll
        for (int ks = 0; ks < 2; ++ks)
#pragma unroll
            for (int ct = 0; ct < 4; ++ct)
                accY[ct] = __builtin_amdgcn_mfma_f32_16x16x32_f16(wfr[ct][4 + ks], xbf[ks], accY[ct], 0, 0, 0);
        if (nrow < nN) {
#pragma unroll
            for (int ct = 0; ct < 4; ++ct) {
                float4 st;
                st.x = accY[ct][0] + bf4[ct].x;
                st.y = accY[ct][1] + bf4[ct].y;
                st.z = accY[ct][2] + bf4[ct].z;
                st.w = accY[ct][3] + bf4[ct].w;
                *(float4*)(out + (size_t)nrow * 64 + ct * 16 + g4 * 4) = st;
            }
        }
    }
}

extern "C" void kernel_launch(void* const* d_in, const int* in_sizes, int n_in,
                              void* d_out, int out_size, void* d_ws, size_t ws_size,
                              hipStream_t stream) {
    const float* x      = (const float*)d_in[0];
    const int*   ei     = (const int*)d_in[1];
    const float* alpha  = (const float*)d_in[2];
    const float* Wself  = (const float*)d_in[3];
    const float* bself  = (const float*)d_in[4];
    const float* preW1  = (const float*)d_in[5];
    const float* preb1  = (const float*)d_in[6];
    const float* postW1 = (const float*)d_in[7];
    const float* postb1 = (const float*)d_in[8];
    const float* linW1  = (const float*)d_in[9];
    const float* linb1  = (const float*)d_in[10];
    const float* preW2  = (const float*)d_in[11];
    const float* preb2  = (const float*)d_in[12];
    const float* postW2 = (const float*)d_in[13];
    const float* postb2 = (const float*)d_in[14];
    const float* linW2  = (const float*)d_in[15];
    const float* linb2  = (const float*)d_in[16];
    float* out = (float*)d_out;
    const int nN = in_sizes[0] / 64;
    const int nE = in_sizes[1] / 2;
    const int nbuck = (nN + 255) >> 8;
    const int nH = nbuck * 256;
    const int nchunk = (nH + 1023) >> 10;

    char* w = (char*)d_ws;
    size_t ofs = 0;
    auto alloc = [&](size_t bytes) {
        char* p = w + ofs;
        ofs = (ofs + bytes + 255) & ~(size_t)255;
        return p;
    };
    half_t* P1   = (half_t*)alloc((size_t)nN * 64 * 2);
    half_t* P2   = (half_t*)alloc((size_t)nN * 64 * 2);
    half_t* Q1   = (half_t*)alloc((size_t)nN * 64 * 2);
    half_t* Q2   = (half_t*)alloc((size_t)nN * 64 * 2);
    half_t* xh   = (half_t*)alloc((size_t)nN * 64 * 2);
    half_t* agg1 = (half_t*)alloc((size_t)nN * 256 * 2);
    half_t* agg2 = (half_t*)alloc((size_t)nN * 256 * 2);
    float* amp1  = (float*)alloc((size_t)nN * 4);
    float* ramp1 = (float*)alloc((size_t)nN * 4);
    float* amp2  = (float*)alloc((size_t)nN * 4);
    float* ramp2 = (float*)alloc((size_t)nN * 4);
    half_t* WLg   = (half_t*)alloc(24 * 16 * 72 * 2);
    half_t* WfinT = (half_t*)alloc(64 * 192 * 2);
    float* bfin   = (float*)alloc(64 * 4);
    int* histD = (int*)alloc(256 * 256 * 4);
    int* histS = (int*)alloc(256 * 256 * 4);
    int* curD  = (int*)alloc((256 * 256 + 1) * 4);
    int* curS  = (int*)alloc((256 * 256 + 1) * 4);
    unsigned* binnedD = (unsigned*)alloc((size_t)nE * 4);
    unsigned* binnedS = (unsigned*)alloc((size_t)nE * 4);
    int* off_dst = (int*)alloc((size_t)(nN + 1) * 4);
    int* off_src = (int*)alloc((size_t)(nN + 1) * 4);
    unsigned short* adj_dst = (unsigned short*)alloc((size_t)nE * 2);
    unsigned short* adj_src = (unsigned short*)alloc((size_t)nE * 2);
    int* bsum = (int*)alloc(2 * 64 * 4);

    k_pre<<<1088, 256, 0, stream>>>(ei, nE, nN, histD, histS,
                                    postW1, postW2, linW1, linW2, Wself, bself,
                                    linb1, linb2, postb1, postb2, alpha,
                                    WLg, WfinT, bfin,
                                    x, preW1, preW2, preb1, preb2,
                                    P1, P2, Q1, Q2, xh);
    k_scanA<<<2 * nchunk, 256, 0, stream>>>(histD, histS, curD, curS, bsum, nH, nchunk);
    k_scanB<<<2 * nchunk, 256, 0, stream>>>(curD, curS, bsum, nH, nchunk);
    k_bin<<<256, 256, 0, stream>>>(ei, nE, nbuck, curD, curS, binnedD, binnedS);
    k_fine<<<2 * nbuck, 256, 0, stream>>>(binnedD, binnedS, curD, curS,
                                          off_dst, off_src, adj_dst, adj_src,
                                          nE, nN, nbuck);
    k_gather<<<2048, 256, 0, stream>>>(P1, P2, Q1, Q2, off_dst, adj_dst, off_src, adj_src,
                                       agg1, agg2, amp1, ramp1, amp2, ramp2, nN, nE);
    k_c<<<512, 256, 0, stream>>>(xh, agg1, agg2, amp1, ramp1, amp2, ramp2,
                                 WLg, WfinT, bfin, out, nN);
}